// Round 1
// baseline (4444.934 us; speedup 1.0000x reference)
//
#include <hip/hip_runtime.h>
#include <stdint.h>

#define T_STEPS 256
#define B_DIM   64
#define MDIM    512
#define NROWS   (T_STEPS * B_DIM)   // 16384
#define KCAT    1024                // [inputs | emb_s]
#define NBIG    3072                // 4M (iou) + M (ctx) + M (wcs)
#define W2ROWS  2560                // 5 gates * 512

typedef short v8s __attribute__((ext_vector_type(8)));
typedef float v4f __attribute__((ext_vector_type(4)));

static __device__ __forceinline__ unsigned short f2bf(float f) {
    unsigned u = __builtin_bit_cast(unsigned, f);
    u += 0x7FFFu + ((u >> 16) & 1u);            // RNE
    return (unsigned short)(u >> 16);
}
static __device__ __forceinline__ float bf2f(unsigned short h) {
    unsigned u = ((unsigned)h) << 16;
    return __builtin_bit_cast(float, u);
}
static __device__ __forceinline__ float sigmoidf(float x) {
    return 1.0f / (1.0f + __expf(-x));
}

// ---------------- prepack kernels ----------------

__global__ void pack_xcat(const float* __restrict__ x, const float* __restrict__ s,
                          unsigned short* __restrict__ xcat) {
    int idx = blockIdx.x * blockDim.x + threadIdx.x;   // over NROWS*KCAT
    if (idx >= NROWS * KCAT) return;
    int row = idx >> 10, col = idx & 1023;
    float v = (col < 512) ? x[row * 512 + col] : s[row * 512 + (col - 512)];
    xcat[idx] = f2bf(v);
}

__global__ void pack_wbig(const float* __restrict__ Wioux, const float* __restrict__ bioux,
                          const float* __restrict__ Wious, const float* __restrict__ bious,
                          const float* __restrict__ Wfx,   const float* __restrict__ bfx,
                          const float* __restrict__ Wwc,   const float* __restrict__ bwc,
                          unsigned short* __restrict__ wbig, float* __restrict__ bbig) {
    int idx = blockIdx.x * blockDim.x + threadIdx.x;   // over NBIG*KCAT
    if (idx >= NBIG * KCAT) return;
    int r = idx >> 10, c = idx & 1023;
    float v;
    if (r < 2048)      v = (c < 512) ? Wioux[r * 512 + c] : Wious[r * 512 + (c - 512)];
    else if (r < 2560) { int j = r - 2048; v = (c < 512) ? Wfx[j * 512 + c] : 0.0f; }
    else               { int j = r - 2560; v = (c < 512) ? 0.0f : Wwc[j * 512 + (c - 512)]; }
    wbig[idx] = f2bf(v);
    if (c == 0) {
        float b;
        if (r < 2048)      b = bioux[r] + bious[r];
        else if (r < 2560) b = bfx[r - 2048];
        else               b = bwc[r - 2560];
        bbig[r] = b;
    }
}

// Pack recurrent weights: per block bk (0..31) owning m-cols [16*bk, 16*bk+16):
// 5 n-tiles of 16 rows: g=0..3 -> W_iouh rows g*512 + m ; g=4 -> W_fh row m
__global__ void pack_w2(const float* __restrict__ Wiouh, const float* __restrict__ biouh,
                        const float* __restrict__ Wfh,   const float* __restrict__ bfh,
                        unsigned short* __restrict__ w2, float* __restrict__ b2) {
    int idx = blockIdx.x * blockDim.x + threadIdx.x;   // over W2ROWS*512
    if (idx >= W2ROWS * 512) return;
    int r = idx >> 9, k = idx & 511;
    int bk = r / 80, rem = r % 80, g = rem >> 4, j = rem & 15;
    int m = bk * 16 + j;
    float v, bias;
    if (g < 4) { v = Wiouh[(size_t)(g * 512 + m) * 512 + k]; bias = biouh[g * 512 + m]; }
    else       { v = Wfh[(size_t)m * 512 + k];               bias = bfh[m]; }
    w2[idx] = f2bf(v);
    if (k == 0) b2[r] = bias;
}

__global__ void init_state(const float* __restrict__ c0, const float* __restrict__ h0,
                           float* __restrict__ cbuf, unsigned short* __restrict__ hbuf0) {
    int idx = blockIdx.x * blockDim.x + threadIdx.x;   // 32768
    if (idx >= B_DIM * MDIM) return;
    cbuf[idx]  = c0[idx];
    hbuf0[idx] = f2bf(h0[idx]);
}

// ---------------- phase 1: Yall[16384,3072] = Xcat @ Wbig^T + b, tanh on cols>=2560 ----------------

__global__ __launch_bounds__(256) void gemm_big(
        const unsigned short* __restrict__ xcat,
        const unsigned short* __restrict__ wbig,
        const float* __restrict__ bbig,
        unsigned short* __restrict__ yall) {
    __shared__ __align__(16) unsigned short As[128][40];  // +8 pad: 2-way LDS aliasing only
    __shared__ __align__(16) unsigned short Bs[128][40];
    int nb = blockIdx.x;              // 0..23 (col block)
    int mb = blockIdx.y;              // 0..127 (row block)
    int tid = threadIdx.x;
    int lane = tid & 63, wid = tid >> 6;
    int wm = wid & 1, wn = wid >> 1;  // 2x2 wave grid, each wave 64x64
    int lm = lane & 15, lq = lane >> 4;
    v4f acc[4][4] = {};
    for (int kb = 0; kb < KCAT / 32; ++kb) {
        __syncthreads();
        #pragma unroll
        for (int it = 0; it < 2; ++it) {
            int cid = tid + it * 256;
            int r = cid >> 2, q = cid & 3;
            *(uint4*)&As[r][q * 8] =
                *(const uint4*)(xcat + (size_t)(mb * 128 + r) * KCAT + kb * 32 + q * 8);
            *(uint4*)&Bs[r][q * 8] =
                *(const uint4*)(wbig + (size_t)(nb * 128 + r) * KCAT + kb * 32 + q * 8);
        }
        __syncthreads();
        v8s a[4], b[4];
        #pragma unroll
        for (int i = 0; i < 4; ++i) a[i] = *(const v8s*)&As[wm * 64 + i * 16 + lm][lq * 8];
        #pragma unroll
        for (int j = 0; j < 4; ++j) b[j] = *(const v8s*)&Bs[wn * 64 + j * 16 + lm][lq * 8];
        #pragma unroll
        for (int i = 0; i < 4; ++i)
            #pragma unroll
            for (int j = 0; j < 4; ++j)
                acc[i][j] = __builtin_amdgcn_mfma_f32_16x16x32_bf16(a[i], b[j], acc[i][j], 0, 0, 0);
    }
    #pragma unroll
    for (int i = 0; i < 4; ++i) {
        int gm = mb * 128 + wm * 64 + i * 16 + lq * 4;
        #pragma unroll
        for (int j = 0; j < 4; ++j) {
            int gn = nb * 128 + wn * 64 + j * 16 + lm;
            float bias = bbig[gn];
            bool do_tanh = (gn >= 2560);
            #pragma unroll
            for (int r = 0; r < 4; ++r) {
                float v = acc[i][j][r] + bias;
                if (do_tanh) v = tanhf(v);
                yall[(size_t)(gm + r) * NBIG + gn] = f2bf(v);
            }
        }
    }
}

// ---------------- phase 2: one kernel per time step ----------------
// 32 blocks x 256 threads. Block bk owns m-cols [16bk,16bk+16).
// GEMM: h[64x512] @ W2slice[80x512]^T -> [64 batch x 5 gate-tiles x 16]

__global__ __launch_bounds__(256) void lstm_step(
        const unsigned short* __restrict__ yall,
        const unsigned short* __restrict__ w2,
        const float* __restrict__ b2,
        const unsigned short* __restrict__ hin,
        unsigned short* __restrict__ hout,
        float* __restrict__ cbuf,
        float* __restrict__ out,
        int t) {
    int bk = blockIdx.x;              // 0..31
    int tid = threadIdx.x;
    int lane = tid & 63, w = tid >> 6;   // wave w owns batch rows [16w,16w+16)
    int lm = lane & 15, lq = lane >> 4;
    v4f acc[5] = {};
    const unsigned short* arow = hin + (size_t)(w * 16 + lm) * 512 + lq * 8;
    const unsigned short* brow = w2 + (size_t)(bk * 80 + lm) * 512 + lq * 8;
    #pragma unroll 2
    for (int kk = 0; kk < 16; ++kk) {
        v8s a = *(const v8s*)(arow + kk * 32);
        #pragma unroll
        for (int g = 0; g < 5; ++g) {
            v8s b = *(const v8s*)(brow + (size_t)g * 16 * 512 + kk * 32);
            acc[g] = __builtin_amdgcn_mfma_f32_16x16x32_bf16(a, b, acc[g], 0, 0, 0);
        }
    }
    int m = bk * 16 + lm;
    float bf_ = b2[(bk * 5 + 0) * 16 + lm];
    float bi_ = b2[(bk * 5 + 1) * 16 + lm];
    float bo_ = b2[(bk * 5 + 2) * 16 + lm];
    float boc = b2[(bk * 5 + 3) * 16 + lm];
    float bct = b2[(bk * 5 + 4) * 16 + lm];
    #pragma unroll
    for (int r = 0; r < 4; ++r) {
        int b_ = w * 16 + lq * 4 + r;
        size_t row = (size_t)t * 64 + b_;
        const unsigned short* yr = yall + row * NBIG;
        float f_ = sigmoidf(bf2f(yr[0 * 512 + m])  + acc[0][r] + bf_);
        float i_ = sigmoidf(bf2f(yr[1 * 512 + m])  + acc[1][r] + bi_);
        float o_ = sigmoidf(bf2f(yr[2 * 512 + m])  + acc[2][r] + bo_);
        float oc = sigmoidf(bf2f(yr[3 * 512 + m])  + acc[3][r] + boc);
        float ct = tanhf(bf2f(yr[4 * 512 + m])     + acc[4][r] + bct);
        float wcs = bf2f(yr[5 * 512 + m]);
        int ci = b_ * 512 + m;
        float cn = i_ * ct + f_ * cbuf[ci];
        cbuf[ci] = cn;
        float hn = o_ * tanhf(cn) + oc * wcs;
        out[row * 512 + m] = hn;
        hout[ci] = f2bf(hn);
    }
}

__global__ void finalize(const float* __restrict__ cbuf, float* __restrict__ out) {
    int idx = blockIdx.x * blockDim.x + threadIdx.x;   // 32768
    if (idx >= B_DIM * MDIM) return;
    const size_t OUT_N = (size_t)T_STEPS * B_DIM * MDIM;        // 8388608
    out[OUT_N + idx] = cbuf[idx];                                // c_fin
    out[OUT_N + B_DIM * MDIM + idx] = out[(size_t)(T_STEPS - 1) * B_DIM * MDIM + idx]; // h_fin
}

// ---------------- launch ----------------

extern "C" void kernel_launch(void* const* d_in, const int* in_sizes, int n_in,
                              void* d_out, int out_size, void* d_ws, size_t ws_size,
                              hipStream_t stream) {
    const float* inputs = (const float*)d_in[0];
    const float* emb_s  = (const float*)d_in[1];
    const float* c0     = (const float*)d_in[2];
    const float* h0     = (const float*)d_in[3];
    const float* W_ioux = (const float*)d_in[4];  const float* b_ioux = (const float*)d_in[5];
    const float* W_iouh = (const float*)d_in[6];  const float* b_iouh = (const float*)d_in[7];
    const float* W_ious = (const float*)d_in[8];  const float* b_ious = (const float*)d_in[9];
    const float* W_fx   = (const float*)d_in[10]; const float* b_fx   = (const float*)d_in[11];
    const float* W_fh   = (const float*)d_in[12]; const float* b_fh   = (const float*)d_in[13];
    const float* W_wc   = (const float*)d_in[14]; const float* b_wc   = (const float*)d_in[15];
    float* out = (float*)d_out;

    char* ws = (char*)d_ws;
    size_t off = 0;
    auto alloc = [&](size_t bytes) -> void* {
        void* p = ws + off;
        off += (bytes + 255) & ~(size_t)255;
        return p;
    };
    unsigned short* yall  = (unsigned short*)alloc((size_t)NROWS * NBIG * 2);   // 100.7 MB
    unsigned short* xcat  = (unsigned short*)alloc((size_t)NROWS * KCAT * 2);   // 33.6 MB
    unsigned short* wbig  = (unsigned short*)alloc((size_t)NBIG * KCAT * 2);    // 6.3 MB
    float*          bbig  = (float*)alloc(NBIG * 4);
    unsigned short* w2    = (unsigned short*)alloc((size_t)W2ROWS * 512 * 2);   // 2.6 MB
    float*          b2    = (float*)alloc(W2ROWS * 4);
    unsigned short* hbuf0 = (unsigned short*)alloc(B_DIM * MDIM * 2);
    unsigned short* hbuf1 = (unsigned short*)alloc(B_DIM * MDIM * 2);
    float*          cbuf  = (float*)alloc(B_DIM * MDIM * 4);

    pack_xcat<<<(NROWS * KCAT + 255) / 256, 256, 0, stream>>>(inputs, emb_s, xcat);
    pack_wbig<<<(NBIG * KCAT + 255) / 256, 256, 0, stream>>>(
        W_ioux, b_ioux, W_ious, b_ious, W_fx, b_fx, W_wc, b_wc, wbig, bbig);
    pack_w2<<<(W2ROWS * 512 + 255) / 256, 256, 0, stream>>>(W_iouh, b_iouh, W_fh, b_fh, w2, b2);
    init_state<<<(B_DIM * MDIM + 255) / 256, 256, 0, stream>>>(c0, h0, cbuf, hbuf0);

    dim3 g1(NBIG / 128, NROWS / 128);
    gemm_big<<<g1, 256, 0, stream>>>(xcat, wbig, bbig, yall);

    for (int t = 0; t < T_STEPS; ++t) {
        const unsigned short* hin = (t & 1) ? hbuf1 : hbuf0;
        unsigned short*      hout = (t & 1) ? hbuf0 : hbuf1;
        lstm_step<<<32, 256, 0, stream>>>(yall, w2, b2, hin, hout, cbuf, out, t);
    }

    finalize<<<(B_DIM * MDIM + 255) / 256, 256, 0, stream>>>(cbuf, out);
}

// Round 2
// 2320.150 us; speedup vs baseline: 1.9158x; 1.9158x over previous
//
#include <hip/hip_runtime.h>
#include <stdint.h>

#define T_STEPS 256
#define B_DIM   64
#define MDIM    512
#define NROWS   (T_STEPS * B_DIM)   // 16384
#define KCAT    1024                // [inputs | emb_s]
#define NBIG    3072                // 4M (iou) + M (ctx) + M (wcs)
#define W2ROWS  2560                // 5 gates * 512
#define NBLK2   32                  // persistent phase-2 blocks
#define OUT_N   ((size_t)T_STEPS * B_DIM * MDIM)  // 8388608

typedef short v8s __attribute__((ext_vector_type(8)));
typedef float v4f __attribute__((ext_vector_type(4)));

static __device__ __forceinline__ unsigned short f2bf(float f) {
    unsigned u = __builtin_bit_cast(unsigned, f);
    u += 0x7FFFu + ((u >> 16) & 1u);            // RNE
    return (unsigned short)(u >> 16);
}
static __device__ __forceinline__ float bf2f(unsigned short h) {
    unsigned u = ((unsigned)h) << 16;
    return __builtin_bit_cast(float, u);
}
static __device__ __forceinline__ float sigmoidf(float x) {
    return 1.0f / (1.0f + __expf(-x));
}

// ---------------- prepack kernels ----------------

__global__ void pack_xcat(const float* __restrict__ x, const float* __restrict__ s,
                          unsigned short* __restrict__ xcat) {
    int idx = blockIdx.x * blockDim.x + threadIdx.x;   // over NROWS*KCAT
    if (idx >= NROWS * KCAT) return;
    int row = idx >> 10, col = idx & 1023;
    float v = (col < 512) ? x[row * 512 + col] : s[row * 512 + (col - 512)];
    xcat[idx] = f2bf(v);
}

__global__ void pack_wbig(const float* __restrict__ Wioux, const float* __restrict__ bioux,
                          const float* __restrict__ Wious, const float* __restrict__ bious,
                          const float* __restrict__ Wfx,   const float* __restrict__ bfx,
                          const float* __restrict__ Wwc,   const float* __restrict__ bwc,
                          unsigned short* __restrict__ wbig, float* __restrict__ bbig) {
    int idx = blockIdx.x * blockDim.x + threadIdx.x;   // over NBIG*KCAT
    if (idx >= NBIG * KCAT) return;
    int r = idx >> 10, c = idx & 1023;
    float v;
    if (r < 2048)      v = (c < 512) ? Wioux[r * 512 + c] : Wious[r * 512 + (c - 512)];
    else if (r < 2560) { int j = r - 2048; v = (c < 512) ? Wfx[j * 512 + c] : 0.0f; }
    else               { int j = r - 2560; v = (c < 512) ? 0.0f : Wwc[j * 512 + (c - 512)]; }
    wbig[idx] = f2bf(v);
    if (c == 0) {
        float b;
        if (r < 2048)      b = bioux[r] + bious[r];
        else if (r < 2560) b = bfx[r - 2048];
        else               b = bwc[r - 2560];
        bbig[r] = b;
    }
}

// Pack recurrent weights: block bk owns m-cols [16*bk,16*bk+16):
// 5 n-tiles of 16 rows: g=0..3 -> W_iouh rows g*512+m ; g=4 -> W_fh row m
__global__ void pack_w2(const float* __restrict__ Wiouh, const float* __restrict__ biouh,
                        const float* __restrict__ Wfh,   const float* __restrict__ bfh,
                        unsigned short* __restrict__ w2, float* __restrict__ b2) {
    int idx = blockIdx.x * blockDim.x + threadIdx.x;   // over W2ROWS*512
    if (idx >= W2ROWS * 512) return;
    int r = idx >> 9, k = idx & 511;
    int bk = r / 80, rem = r % 80, g = rem >> 4, j = rem & 15;
    int m = bk * 16 + j;
    float v, bias;
    if (g < 4) { v = Wiouh[(size_t)(g * 512 + m) * 512 + k]; bias = biouh[g * 512 + m]; }
    else       { v = Wfh[(size_t)m * 512 + k];               bias = bfh[m]; }
    w2[idx] = f2bf(v);
    if (k == 0) b2[r] = bias;
}

__global__ void init_state(const float* __restrict__ h0,
                           unsigned short* __restrict__ hbuf0,
                           int* __restrict__ cnt) {
    int idx = blockIdx.x * blockDim.x + threadIdx.x;   // 32768
    if (idx >= B_DIM * MDIM) return;
    hbuf0[idx] = f2bf(h0[idx]);
    if (idx == 0) *cnt = 0;
}

// ---------------- phase 1: Yall[16384,3072] = Xcat @ Wbig^T + b, tanh on cols>=2560 ----------------

__global__ __launch_bounds__(256) void gemm_big(
        const unsigned short* __restrict__ xcat,
        const unsigned short* __restrict__ wbig,
        const float* __restrict__ bbig,
        unsigned short* __restrict__ yall) {
    __shared__ __align__(16) unsigned short As[128][40];
    __shared__ __align__(16) unsigned short Bs[128][40];
    int nb = blockIdx.x;              // 0..23 (col block)
    int mb = blockIdx.y;              // 0..127 (row block)
    int tid = threadIdx.x;
    int lane = tid & 63, wid = tid >> 6;
    int wm = wid & 1, wn = wid >> 1;  // 2x2 wave grid, each wave 64x64
    int lm = lane & 15, lq = lane >> 4;
    v4f acc[4][4] = {};
    for (int kb = 0; kb < KCAT / 32; ++kb) {
        __syncthreads();
        #pragma unroll
        for (int it = 0; it < 2; ++it) {
            int cid = tid + it * 256;
            int r = cid >> 2, q = cid & 3;
            *(uint4*)&As[r][q * 8] =
                *(const uint4*)(xcat + (size_t)(mb * 128 + r) * KCAT + kb * 32 + q * 8);
            *(uint4*)&Bs[r][q * 8] =
                *(const uint4*)(wbig + (size_t)(nb * 128 + r) * KCAT + kb * 32 + q * 8);
        }
        __syncthreads();
        v8s a[4], b[4];
        #pragma unroll
        for (int i = 0; i < 4; ++i) a[i] = *(const v8s*)&As[wm * 64 + i * 16 + lm][lq * 8];
        #pragma unroll
        for (int j = 0; j < 4; ++j) b[j] = *(const v8s*)&Bs[wn * 64 + j * 16 + lm][lq * 8];
        #pragma unroll
        for (int i = 0; i < 4; ++i)
            #pragma unroll
            for (int j = 0; j < 4; ++j)
                acc[i][j] = __builtin_amdgcn_mfma_f32_16x16x32_bf16(a[i], b[j], acc[i][j], 0, 0, 0);
    }
    #pragma unroll
    for (int i = 0; i < 4; ++i) {
        int gm = mb * 128 + wm * 64 + i * 16 + lq * 4;
        #pragma unroll
        for (int j = 0; j < 4; ++j) {
            int gn = nb * 128 + wn * 64 + j * 16 + lm;
            float bias = bbig[gn];
            bool do_tanh = (gn >= 2560);
            #pragma unroll
            for (int r = 0; r < 4; ++r) {
                float v = acc[i][j][r] + bias;
                if (do_tanh) v = tanhf(v);
                yall[(size_t)(gm + r) * NBIG + gn] = f2bf(v);
            }
        }
    }
}

// ---------------- phase 2: ONE persistent kernel, grid barrier per step ----------------
// 32 blocks x 256 threads. Block bk owns m-cols [16bk,16bk+16) -> 80 W2 rows (5 gate tiles).
// Wave (p,q): batch-half p (rows p*32..p*32+32, 2 MFMA tiles), K-half q (kk = q*8..q*8+8).
// B fragments (5 gates x 8 kk = 160 VGPRs) live in registers for all 256 steps.
// q=1 waves write K-partials to LDS; q=0 waves reduce + epilogue (c state in registers).
// yall slice for step t+1 prefetched into LDS via global_load_lds by q=1 waves during step t.

__device__ __forceinline__ void grid_barrier(int* cnt, int target) {
    __syncthreads();
    if (threadIdx.x == 0) {
        __hip_atomic_fetch_add(cnt, 1, __ATOMIC_ACQ_REL, __HIP_MEMORY_SCOPE_AGENT);
        while (__hip_atomic_load(cnt, __ATOMIC_ACQUIRE, __HIP_MEMORY_SCOPE_AGENT) < target)
            __builtin_amdgcn_s_sleep(1);
    }
    __syncthreads();
}

__global__ __launch_bounds__(256, 1) void lstm_persist(
        const unsigned short* __restrict__ yall,
        const unsigned short* __restrict__ w2,
        const float* __restrict__ b2,
        const float* __restrict__ c0,
        unsigned short* __restrict__ hbuf0,
        unsigned short* __restrict__ hbuf1,
        float* __restrict__ out,
        int* __restrict__ cnt) {
    __shared__ __align__(16) float red[2][10][256];                 // 20 KB: K-partials
    __shared__ __align__(16) unsigned short ybuf[2][64][6][16];     // 24 KB: y slices (dbuf)
    int bk = blockIdx.x;
    int tid = threadIdx.x;
    int lane = tid & 63, wid = tid >> 6;
    int p = wid >> 1;                 // batch half
    int q = wid & 1;                  // K half
    int lm = lane & 15, lq = lane >> 4;
    int m = bk * 16 + lm;

    // B fragments in registers: gate g, kk = q*8+j
    v8s bfrag[5][8];
    const unsigned short* w2b = w2 + (size_t)(bk * 80 + lm) * 512 + lq * 8;
    #pragma unroll
    for (int g = 0; g < 5; ++g)
        #pragma unroll
        for (int j = 0; j < 8; ++j)
            bfrag[g][j] = *(const v8s*)(w2b + (size_t)g * 16 * 512 + (q * 8 + j) * 32);

    // biases + c state (used by q==0 epilogue waves)
    float bias[5];
    #pragma unroll
    for (int g = 0; g < 5; ++g) bias[g] = b2[(bk * 5 + g) * 16 + lm];
    float creg[2][4];
    #pragma unroll
    for (int tb = 0; tb < 2; ++tb)
        #pragma unroll
        for (int r = 0; r < 4; ++r)
            creg[tb][r] = c0[(p * 32 + tb * 16 + lq * 4 + r) * 512 + m];

    // initial y prefetch (t=0 -> buf 0) by q==1 waves
    if (q == 1) {
        #pragma unroll
        for (int i = 0; i < 6; ++i) {
            int c = (p * 6 + i) * 64 + lane;
            int b = c / 12, rem = c % 12, g = rem >> 1, half = rem & 1;
            int gcol = (g < 4) ? g * 512 : (g == 4 ? 2048 : 2560);
            const unsigned short* gp = yall + (size_t)b * NBIG + gcol + bk * 16 + half * 8;
            unsigned short* lp = &ybuf[0][0][0][0] + (p * 6 + i) * 512;
            __builtin_amdgcn_global_load_lds(
                (const __attribute__((address_space(1))) unsigned int*)gp,
                (__attribute__((address_space(3))) unsigned int*)lp, 16, 0, 0);
        }
    }

    for (int t = 0; t < T_STEPS; ++t) {
        const unsigned short* hin = (t & 1) ? hbuf1 : hbuf0;
        unsigned short*      hout = (t & 1) ? hbuf0 : hbuf1;
        v4f acc[2][5] = {};
        const unsigned short* ha = hin + (size_t)(p * 32 + lm) * 512 + q * 256 + lq * 8;
        #pragma unroll
        for (int j = 0; j < 8; ++j) {
            v8s a0 = *(const v8s*)(ha + j * 32);
            v8s a1 = *(const v8s*)(ha + 16 * 512 + j * 32);
            #pragma unroll
            for (int g = 0; g < 5; ++g) {
                acc[0][g] = __builtin_amdgcn_mfma_f32_16x16x32_bf16(a0, bfrag[g][j], acc[0][g], 0, 0, 0);
                acc[1][g] = __builtin_amdgcn_mfma_f32_16x16x32_bf16(a1, bfrag[g][j], acc[1][g], 0, 0, 0);
            }
        }
        if (q == 1) {   // publish K-partials
            #pragma unroll
            for (int tb = 0; tb < 2; ++tb)
                #pragma unroll
                for (int g = 0; g < 5; ++g)
                    *(v4f*)&red[p][tb * 5 + g][lane * 4] = acc[tb][g];
        }
        __syncthreads();
        if (q == 0) {   // reduce + epilogue
            #pragma unroll
            for (int tb = 0; tb < 2; ++tb)
                #pragma unroll
                for (int g = 0; g < 5; ++g)
                    acc[tb][g] += *(const v4f*)&red[p][tb * 5 + g][lane * 4];
            const unsigned short* yb = &ybuf[t & 1][0][0][0];
            #pragma unroll
            for (int tb = 0; tb < 2; ++tb) {
                #pragma unroll
                for (int r = 0; r < 4; ++r) {
                    int brow = p * 32 + tb * 16 + lq * 4 + r;
                    const unsigned short* ybr = yb + brow * 96;
                    float f_ = sigmoidf(bf2f(ybr[0 * 16 + lm]) + acc[tb][0][r] + bias[0]);
                    float i_ = sigmoidf(bf2f(ybr[1 * 16 + lm]) + acc[tb][1][r] + bias[1]);
                    float o_ = sigmoidf(bf2f(ybr[2 * 16 + lm]) + acc[tb][2][r] + bias[2]);
                    float oc = sigmoidf(bf2f(ybr[3 * 16 + lm]) + acc[tb][3][r] + bias[3]);
                    float ct = tanhf  (bf2f(ybr[4 * 16 + lm]) + acc[tb][4][r] + bias[4]);
                    float wcs = bf2f(ybr[5 * 16 + lm]);
                    float cn = i_ * ct + f_ * creg[tb][r];
                    creg[tb][r] = cn;
                    float hn = o_ * tanhf(cn) + oc * wcs;
                    out[((size_t)t * 64 + brow) * 512 + m] = hn;
                    hout[brow * 512 + m] = f2bf(hn);
                    if (t == T_STEPS - 1)
                        out[OUT_N + 32768 + (size_t)brow * 512 + m] = hn;   // h_fin
                }
            }
        } else if (t + 1 < T_STEPS) {   // prefetch y for t+1
            int buf = (t + 1) & 1;
            #pragma unroll
            for (int i = 0; i < 6; ++i) {
                int c = (p * 6 + i) * 64 + lane;
                int b = c / 12, rem = c % 12, g = rem >> 1, half = rem & 1;
                int gcol = (g < 4) ? g * 512 : (g == 4 ? 2048 : 2560);
                const unsigned short* gp = yall + ((size_t)(t + 1) * 64 + b) * NBIG + gcol + bk * 16 + half * 8;
                unsigned short* lp = &ybuf[buf][0][0][0] + (p * 6 + i) * 512;
                __builtin_amdgcn_global_load_lds(
                    (const __attribute__((address_space(1))) unsigned int*)gp,
                    (__attribute__((address_space(3))) unsigned int*)lp, 16, 0, 0);
            }
        }
        grid_barrier(cnt, NBLK2 * (t + 1));
    }

    // c_fin
    if (q == 0) {
        #pragma unroll
        for (int tb = 0; tb < 2; ++tb)
            #pragma unroll
            for (int r = 0; r < 4; ++r)
                out[OUT_N + (size_t)(p * 32 + tb * 16 + lq * 4 + r) * 512 + m] = creg[tb][r];
    }
}

// ---------------- launch ----------------

extern "C" void kernel_launch(void* const* d_in, const int* in_sizes, int n_in,
                              void* d_out, int out_size, void* d_ws, size_t ws_size,
                              hipStream_t stream) {
    const float* inputs = (const float*)d_in[0];
    const float* emb_s  = (const float*)d_in[1];
    const float* c0     = (const float*)d_in[2];
    const float* h0     = (const float*)d_in[3];
    const float* W_ioux = (const float*)d_in[4];  const float* b_ioux = (const float*)d_in[5];
    const float* W_iouh = (const float*)d_in[6];  const float* b_iouh = (const float*)d_in[7];
    const float* W_ious = (const float*)d_in[8];  const float* b_ious = (const float*)d_in[9];
    const float* W_fx   = (const float*)d_in[10]; const float* b_fx   = (const float*)d_in[11];
    const float* W_fh   = (const float*)d_in[12]; const float* b_fh   = (const float*)d_in[13];
    const float* W_wc   = (const float*)d_in[14]; const float* b_wc   = (const float*)d_in[15];
    float* out = (float*)d_out;

    char* ws = (char*)d_ws;
    size_t off = 0;
    auto alloc = [&](size_t bytes) -> void* {
        void* p = ws + off;
        off += (bytes + 255) & ~(size_t)255;
        return p;
    };
    unsigned short* yall  = (unsigned short*)alloc((size_t)NROWS * NBIG * 2);   // 100.7 MB
    unsigned short* xcat  = (unsigned short*)alloc((size_t)NROWS * KCAT * 2);   // 33.6 MB
    unsigned short* wbig  = (unsigned short*)alloc((size_t)NBIG * KCAT * 2);    // 6.3 MB
    float*          bbig  = (float*)alloc(NBIG * 4);
    unsigned short* w2    = (unsigned short*)alloc((size_t)W2ROWS * 512 * 2);   // 2.6 MB
    float*          b2    = (float*)alloc(W2ROWS * 4);
    unsigned short* hbuf0 = (unsigned short*)alloc(B_DIM * MDIM * 2);
    unsigned short* hbuf1 = (unsigned short*)alloc(B_DIM * MDIM * 2);
    int*            cnt   = (int*)alloc(256);

    pack_xcat<<<(NROWS * KCAT + 255) / 256, 256, 0, stream>>>(inputs, emb_s, xcat);
    pack_wbig<<<(NBIG * KCAT + 255) / 256, 256, 0, stream>>>(
        W_ioux, b_ioux, W_ious, b_ious, W_fx, b_fx, W_wc, b_wc, wbig, bbig);
    pack_w2<<<(W2ROWS * 512 + 255) / 256, 256, 0, stream>>>(W_iouh, b_iouh, W_fh, b_fh, w2, b2);
    init_state<<<(B_DIM * MDIM + 255) / 256, 256, 0, stream>>>(h0, hbuf0, cnt);

    dim3 g1(NBIG / 128, NROWS / 128);
    gemm_big<<<g1, 256, 0, stream>>>(xcat, wbig, bbig, yall);

    lstm_persist<<<NBLK2, 256, 0, stream>>>(yall, w2, b2, c0, hbuf0, hbuf1, out, cnt);
}